// Round 1
// baseline (1501.974 us; speedup 1.0000x reference)
//
#include <hip/hip_runtime.h>
#include <math.h>

#define NUM_USERS 100000
#define NUM_ITEMS 200000
#define N_NODES   300000   // NUM_USERS + NUM_ITEMS
#define EMB       64
#define NUM_INTER 1000000
#define BATCH     16384

// ---------- kernels ----------

__global__ void softmax4_k(const float* __restrict__ lw, float* __restrict__ w) {
    if (threadIdx.x == 0 && blockIdx.x == 0) {
        float a = lw[0], b = lw[1], c = lw[2], d = lw[3];
        float m = fmaxf(fmaxf(a, b), fmaxf(c, d));
        float e0 = expf(a - m), e1 = expf(b - m), e2 = expf(c - m), e3 = expf(d - m);
        float s = e0 + e1 + e2 + e3;
        w[0] = e0 / s; w[1] = e1 / s; w[2] = e2 / s; w[3] = e3 / s;
    }
}

__global__ void degree_k(const int* __restrict__ iu, const int* __restrict__ ii,
                         float* __restrict__ deg) {
    int e = blockIdx.x * blockDim.x + threadIdx.x;
    if (e < NUM_INTER) {
        atomicAdd(&deg[iu[e]], 1.0f);
        atomicAdd(&deg[NUM_USERS + ii[e]], 1.0f);
    }
}

__global__ void dinv_k(const float* __restrict__ deg, float* __restrict__ dinv) {
    int n = blockIdx.x * blockDim.x + threadIdx.x;
    if (n < N_NODES) {
        float d = deg[n];
        dinv[n] = (d > 0.0f) ? (1.0f / sqrtf(d)) : 0.0f;
    }
}

// one lane per (interaction, dim): both directed edges handled here
__global__ void prop_k(const int* __restrict__ iu, const int* __restrict__ ii,
                       const float* __restrict__ dinv,
                       const float* __restrict__ in, float* __restrict__ out) {
    int idx = blockIdx.x * blockDim.x + threadIdx.x;   // < NUM_INTER*64
    int e = idx >> 6;
    int d = idx & 63;
    if (e < NUM_INTER) {
        int u  = iu[e];
        int it = NUM_USERS + ii[e];
        float w = dinv[u] * dinv[it];
        float a = in[it * EMB + d];   // item row (coalesced across the wave)
        float b = in[u  * EMB + d];   // user row
        atomicAdd(&out[u  * EMB + d], w * a);
        atomicAdd(&out[it * EMB + d], w * b);
    }
}

// layer 0: final = w0 * emb at the queried nodes (also initializes fu/fi)
__global__ void gather0_k(const float* __restrict__ ue, const float* __restrict__ ie,
                          const int* __restrict__ uid, const int* __restrict__ iid,
                          const float* __restrict__ w,
                          float* __restrict__ fu, float* __restrict__ fi) {
    int idx = blockIdx.x * blockDim.x + threadIdx.x;   // < BATCH*64
    if (idx < BATCH * EMB) {
        int b = idx >> 6, d = idx & 63;
        float w0 = w[0];
        fu[idx] = w0 * ue[uid[b] * EMB + d];
        fi[idx] = w0 * ie[iid[b] * EMB + d];
    }
}

__global__ void gather_acc_k(const float* __restrict__ emb,
                             const int* __restrict__ uid, const int* __restrict__ iid,
                             const float* __restrict__ w, int wi,
                             float* __restrict__ fu, float* __restrict__ fi) {
    int idx = blockIdx.x * blockDim.x + threadIdx.x;
    if (idx < BATCH * EMB) {
        int b = idx >> 6, d = idx & 63;
        float wl = w[wi];
        fu[idx] += wl * emb[uid[b] * EMB + d];
        fi[idx] += wl * emb[(NUM_USERS + iid[b]) * EMB + d];
    }
}

__global__ void score_k(const float* __restrict__ fu, const float* __restrict__ fi,
                        float* __restrict__ out) {
    int idx = blockIdx.x * blockDim.x + threadIdx.x;   // < BATCH*64
    int b = idx >> 6, d = idx & 63;
    float v = fu[idx] * fi[idx];
    #pragma unroll
    for (int off = 32; off > 0; off >>= 1)
        v += __shfl_down(v, off, 64);
    if (d == 0) out[b] = v;
}

// ---------- launch ----------

extern "C" void kernel_launch(void* const* d_in, const int* in_sizes, int n_in,
                              void* d_out, int out_size, void* d_ws, size_t ws_size,
                              hipStream_t stream) {
    const float* user_emb = (const float*)d_in[0];
    const float* item_emb = (const float*)d_in[1];
    const float* layer_w  = (const float*)d_in[2];
    const int*   inter_u  = (const int*)d_in[3];
    const int*   inter_i  = (const int*)d_in[4];
    const int*   user_ids = (const int*)d_in[5];
    const int*   item_ids = (const int*)d_in[6];
    float* out = (float*)d_out;

    // workspace layout (256B aligned slices)
    char* base = (char*)d_ws;
    size_t off = 0;
    auto alloc = [&](size_t bytes) -> char* {
        char* p = base + off;
        off = (off + bytes + 255) & ~(size_t)255;
        return p;
    };
    float* w4   = (float*)alloc(4 * sizeof(float));
    float* deg  = (float*)alloc((size_t)N_NODES * sizeof(float));
    float* dinv = (float*)alloc((size_t)N_NODES * sizeof(float));
    float* emb0 = (float*)alloc((size_t)N_NODES * EMB * sizeof(float));
    float* emb1 = (float*)alloc((size_t)N_NODES * EMB * sizeof(float));
    float* fu   = (float*)alloc((size_t)BATCH * EMB * sizeof(float));
    float* fi   = (float*)alloc((size_t)BATCH * EMB * sizeof(float));

    // 1. softmax weights
    softmax4_k<<<1, 64, 0, stream>>>(layer_w, w4);

    // 2. degrees
    hipMemsetAsync(deg, 0, (size_t)N_NODES * sizeof(float), stream);
    degree_k<<<(NUM_INTER + 255) / 256, 256, 0, stream>>>(inter_u, inter_i, deg);
    dinv_k<<<(N_NODES + 255) / 256, 256, 0, stream>>>(deg, dinv);

    // 3. emb0 = concat(user_emb, item_emb)
    hipMemcpyAsync(emb0, user_emb, (size_t)NUM_USERS * EMB * sizeof(float),
                   hipMemcpyDeviceToDevice, stream);
    hipMemcpyAsync(emb0 + (size_t)NUM_USERS * EMB, item_emb,
                   (size_t)NUM_ITEMS * EMB * sizeof(float),
                   hipMemcpyDeviceToDevice, stream);

    // 4. layer-0 contribution at queried nodes
    gather0_k<<<(BATCH * EMB + 255) / 256, 256, 0, stream>>>(
        user_emb, item_emb, user_ids, item_ids, w4, fu, fi);

    // 5. 3 propagation layers, ping-pong emb0/emb1
    float* cur = emb0;
    float* nxt = emb1;
    const int prop_blocks = (NUM_INTER * EMB) / 256;   // 64M threads / 256
    for (int layer = 0; layer < 3; ++layer) {
        hipMemsetAsync(nxt, 0, (size_t)N_NODES * EMB * sizeof(float), stream);
        prop_k<<<prop_blocks, 256, 0, stream>>>(inter_u, inter_i, dinv, cur, nxt);
        gather_acc_k<<<(BATCH * EMB + 255) / 256, 256, 0, stream>>>(
            nxt, user_ids, item_ids, w4, layer + 1, fu, fi);
        float* t = cur; cur = nxt; nxt = t;
    }

    // 6. scores
    score_k<<<(BATCH * EMB + 255) / 256, 256, 0, stream>>>(fu, fi, out);
}

// Round 2
// 753.977 us; speedup vs baseline: 1.9921x; 1.9921x over previous
//
#include <hip/hip_runtime.h>
#include <math.h>

#define NUM_USERS 100000
#define NUM_ITEMS 200000
#define N_NODES   300000   // NUM_USERS + NUM_ITEMS
#define EMB       64
#define NUM_INTER 1000000
#define N_EDGES   (2 * NUM_INTER)
#define BATCH     16384
#define SCAN_BLOCK 1024

// ---------- small kernels ----------

__global__ void softmax4_k(const float* __restrict__ lw, float* __restrict__ w) {
    if (threadIdx.x == 0 && blockIdx.x == 0) {
        float a = lw[0], b = lw[1], c = lw[2], d = lw[3];
        float m = fmaxf(fmaxf(a, b), fmaxf(c, d));
        float e0 = expf(a - m), e1 = expf(b - m), e2 = expf(c - m), e3 = expf(d - m);
        float s = e0 + e1 + e2 + e3;
        w[0] = e0 / s; w[1] = e1 / s; w[2] = e2 / s; w[3] = e3 / s;
    }
}

__global__ void degree_k(const int* __restrict__ iu, const int* __restrict__ ii,
                         int* __restrict__ deg) {
    int e = blockIdx.x * blockDim.x + threadIdx.x;
    if (e < NUM_INTER) {
        atomicAdd(&deg[iu[e]], 1);
        atomicAdd(&deg[NUM_USERS + ii[e]], 1);
    }
}

__global__ void dinv_k(const int* __restrict__ deg, float* __restrict__ dinv) {
    int n = blockIdx.x * blockDim.x + threadIdx.x;
    if (n < N_NODES) {
        int d = deg[n];
        dinv[n] = (d > 0) ? (1.0f / sqrtf((float)d)) : 0.0f;
    }
}

// ---------- exclusive scan of deg -> row_start (3 kernels) ----------

__global__ void block_sum_k(const int* __restrict__ deg, int* __restrict__ bsum, int n) {
    __shared__ int lds[SCAN_BLOCK];
    int g = blockIdx.x * SCAN_BLOCK + threadIdx.x;
    lds[threadIdx.x] = (g < n) ? deg[g] : 0;
    __syncthreads();
    for (int s = SCAN_BLOCK / 2; s > 0; s >>= 1) {
        if (threadIdx.x < s) lds[threadIdx.x] += lds[threadIdx.x + s];
        __syncthreads();
    }
    if (threadIdx.x == 0) bsum[blockIdx.x] = lds[0];
}

// single block; nb <= 512
__global__ void scan_bsum_k(int* __restrict__ bsum, int nb) {
    __shared__ int lds[512];
    int t = threadIdx.x;
    int v = (t < nb) ? bsum[t] : 0;
    lds[t] = v;
    __syncthreads();
    for (int ofs = 1; ofs < 512; ofs <<= 1) {
        int x = (t >= ofs) ? lds[t - ofs] : 0;
        __syncthreads();
        lds[t] += x;
        __syncthreads();
    }
    if (t < nb) bsum[t] = lds[t] - v;   // exclusive
}

__global__ void scan_block_k(const int* __restrict__ deg, const int* __restrict__ bsum,
                             int* __restrict__ row_start, int n) {
    __shared__ int lds[SCAN_BLOCK];
    int g = blockIdx.x * SCAN_BLOCK + threadIdx.x;
    int v = (g < n) ? deg[g] : 0;
    lds[threadIdx.x] = v;
    __syncthreads();
    for (int ofs = 1; ofs < SCAN_BLOCK; ofs <<= 1) {
        int x = (threadIdx.x >= ofs) ? lds[threadIdx.x - ofs] : 0;
        __syncthreads();
        lds[threadIdx.x] += x;
        __syncthreads();
    }
    if (g < n) row_start[g] = bsum[blockIdx.x] + lds[threadIdx.x] - v;  // exclusive
    if (g == 0 && blockIdx.x == 0) row_start[n] = N_EDGES;
}

// ---------- CSR fill ----------

__global__ void fill_csr_k(const int* __restrict__ iu, const int* __restrict__ ii,
                           const int* __restrict__ row_start,
                           int* __restrict__ fill, int* __restrict__ nbr) {
    int e = blockIdx.x * blockDim.x + threadIdx.x;
    if (e < NUM_INTER) {
        int u  = iu[e];
        int it = NUM_USERS + ii[e];
        int p0 = row_start[u]  + atomicAdd(&fill[u],  1);
        nbr[p0] = it;
        int p1 = row_start[it] + atomicAdd(&fill[it], 1);
        nbr[p1] = u;
    }
}

// ---------- propagation: one wave per node, lane = dim ----------

// first layer reads from the two raw input tables (no concat copy needed)
__global__ void prop_first_k(const int* __restrict__ row_start, const int* __restrict__ nbr,
                             const float* __restrict__ dinv,
                             const float* __restrict__ ue, const float* __restrict__ ie,
                             float* __restrict__ out) {
    int wave = (blockIdx.x * blockDim.x + threadIdx.x) >> 6;
    int lane = threadIdx.x & 63;
    if (wave >= N_NODES) return;
    int beg = row_start[wave], end = row_start[wave + 1];
    float acc = 0.0f;
    int j = beg;
    for (; j + 4 <= end; j += 4) {
        int n0 = nbr[j], n1 = nbr[j + 1], n2 = nbr[j + 2], n3 = nbr[j + 3];
        const float* s0 = (n0 < NUM_USERS) ? ue + (size_t)n0 * EMB : ie + (size_t)(n0 - NUM_USERS) * EMB;
        const float* s1 = (n1 < NUM_USERS) ? ue + (size_t)n1 * EMB : ie + (size_t)(n1 - NUM_USERS) * EMB;
        const float* s2 = (n2 < NUM_USERS) ? ue + (size_t)n2 * EMB : ie + (size_t)(n2 - NUM_USERS) * EMB;
        const float* s3 = (n3 < NUM_USERS) ? ue + (size_t)n3 * EMB : ie + (size_t)(n3 - NUM_USERS) * EMB;
        float w0 = dinv[n0], w1 = dinv[n1], w2 = dinv[n2], w3 = dinv[n3];
        acc += w0 * s0[lane] + w1 * s1[lane] + w2 * s2[lane] + w3 * s3[lane];
    }
    for (; j < end; ++j) {
        int n0 = nbr[j];
        const float* s0 = (n0 < NUM_USERS) ? ue + (size_t)n0 * EMB : ie + (size_t)(n0 - NUM_USERS) * EMB;
        acc += dinv[n0] * s0[lane];
    }
    out[(size_t)wave * EMB + lane] = dinv[wave] * acc;
}

__global__ void prop_k(const int* __restrict__ row_start, const int* __restrict__ nbr,
                       const float* __restrict__ dinv,
                       const float* __restrict__ in, float* __restrict__ out) {
    int wave = (blockIdx.x * blockDim.x + threadIdx.x) >> 6;
    int lane = threadIdx.x & 63;
    if (wave >= N_NODES) return;
    int beg = row_start[wave], end = row_start[wave + 1];
    float acc = 0.0f;
    int j = beg;
    for (; j + 4 <= end; j += 4) {
        int n0 = nbr[j], n1 = nbr[j + 1], n2 = nbr[j + 2], n3 = nbr[j + 3];
        float w0 = dinv[n0], w1 = dinv[n1], w2 = dinv[n2], w3 = dinv[n3];
        acc += w0 * in[(size_t)n0 * EMB + lane] + w1 * in[(size_t)n1 * EMB + lane]
             + w2 * in[(size_t)n2 * EMB + lane] + w3 * in[(size_t)n3 * EMB + lane];
    }
    for (; j < end; ++j) {
        int n0 = nbr[j];
        acc += dinv[n0] * in[(size_t)n0 * EMB + lane];
    }
    out[(size_t)wave * EMB + lane] = dinv[wave] * acc;
}

// ---------- epilogue ----------

__global__ void gather0_k(const float* __restrict__ ue, const float* __restrict__ ie,
                          const int* __restrict__ uid, const int* __restrict__ iid,
                          const float* __restrict__ w,
                          float* __restrict__ fu, float* __restrict__ fi) {
    int idx = blockIdx.x * blockDim.x + threadIdx.x;
    if (idx < BATCH * EMB) {
        int b = idx >> 6, d = idx & 63;
        float w0 = w[0];
        fu[idx] = w0 * ue[(size_t)uid[b] * EMB + d];
        fi[idx] = w0 * ie[(size_t)iid[b] * EMB + d];
    }
}

__global__ void gather_acc_k(const float* __restrict__ emb,
                             const int* __restrict__ uid, const int* __restrict__ iid,
                             const float* __restrict__ w, int wi,
                             float* __restrict__ fu, float* __restrict__ fi) {
    int idx = blockIdx.x * blockDim.x + threadIdx.x;
    if (idx < BATCH * EMB) {
        int b = idx >> 6, d = idx & 63;
        float wl = w[wi];
        fu[idx] += wl * emb[(size_t)uid[b] * EMB + d];
        fi[idx] += wl * emb[((size_t)NUM_USERS + iid[b]) * EMB + d];
    }
}

__global__ void score_k(const float* __restrict__ fu, const float* __restrict__ fi,
                        float* __restrict__ out) {
    int idx = blockIdx.x * blockDim.x + threadIdx.x;
    int b = idx >> 6, d = idx & 63;
    float v = fu[idx] * fi[idx];
    #pragma unroll
    for (int off = 32; off > 0; off >>= 1)
        v += __shfl_down(v, off, 64);
    if (d == 0) out[b] = v;
}

// ---------- launch ----------

extern "C" void kernel_launch(void* const* d_in, const int* in_sizes, int n_in,
                              void* d_out, int out_size, void* d_ws, size_t ws_size,
                              hipStream_t stream) {
    const float* user_emb = (const float*)d_in[0];
    const float* item_emb = (const float*)d_in[1];
    const float* layer_w  = (const float*)d_in[2];
    const int*   inter_u  = (const int*)d_in[3];
    const int*   inter_i  = (const int*)d_in[4];
    const int*   user_ids = (const int*)d_in[5];
    const int*   item_ids = (const int*)d_in[6];
    float* out = (float*)d_out;

    char* base = (char*)d_ws;
    size_t off = 0;
    auto alloc = [&](size_t bytes) -> char* {
        char* p = base + off;
        off = (off + bytes + 255) & ~(size_t)255;
        return p;
    };
    float* w4        = (float*)alloc(4 * sizeof(float));
    int*   deg       = (int*)  alloc((size_t)N_NODES * sizeof(int));
    float* dinv      = (float*)alloc((size_t)N_NODES * sizeof(float));
    int*   row_start = (int*)  alloc(((size_t)N_NODES + 1) * sizeof(int));
    int*   bsum      = (int*)  alloc(512 * sizeof(int));
    int*   fill      = (int*)  alloc((size_t)N_NODES * sizeof(int));
    int*   csr_nbr   = (int*)  alloc((size_t)N_EDGES * sizeof(int));
    float* emb0      = (float*)alloc((size_t)N_NODES * EMB * sizeof(float));
    float* emb1      = (float*)alloc((size_t)N_NODES * EMB * sizeof(float));
    float* fu        = (float*)alloc((size_t)BATCH * EMB * sizeof(float));
    float* fi        = (float*)alloc((size_t)BATCH * EMB * sizeof(float));

    const int nscan_blocks = (N_NODES + SCAN_BLOCK - 1) / SCAN_BLOCK;   // 293

    // 1. softmax weights
    softmax4_k<<<1, 64, 0, stream>>>(layer_w, w4);

    // 2. degrees + dinv
    hipMemsetAsync(deg, 0, (size_t)N_NODES * sizeof(int), stream);
    degree_k<<<(NUM_INTER + 255) / 256, 256, 0, stream>>>(inter_u, inter_i, deg);
    dinv_k<<<(N_NODES + 255) / 256, 256, 0, stream>>>(deg, dinv);

    // 3. exclusive scan deg -> row_start
    block_sum_k<<<nscan_blocks, SCAN_BLOCK, 0, stream>>>(deg, bsum, N_NODES);
    scan_bsum_k<<<1, 512, 0, stream>>>(bsum, nscan_blocks);
    scan_block_k<<<nscan_blocks, SCAN_BLOCK, 0, stream>>>(deg, bsum, row_start, N_NODES);

    // 4. CSR fill
    hipMemsetAsync(fill, 0, (size_t)N_NODES * sizeof(int), stream);
    fill_csr_k<<<(NUM_INTER + 255) / 256, 256, 0, stream>>>(inter_u, inter_i, row_start,
                                                            fill, csr_nbr);

    // 5. layer-0 contribution at queried nodes
    gather0_k<<<(BATCH * EMB + 255) / 256, 256, 0, stream>>>(
        user_emb, item_emb, user_ids, item_ids, w4, fu, fi);

    // 6. 3 propagation layers (gather-based, no atomics, no memsets)
    const int prop_blocks = ((size_t)N_NODES * EMB + 255) / 256;
    prop_first_k<<<prop_blocks, 256, 0, stream>>>(row_start, csr_nbr, dinv,
                                                  user_emb, item_emb, emb0);
    gather_acc_k<<<(BATCH * EMB + 255) / 256, 256, 0, stream>>>(
        emb0, user_ids, item_ids, w4, 1, fu, fi);

    prop_k<<<prop_blocks, 256, 0, stream>>>(row_start, csr_nbr, dinv, emb0, emb1);
    gather_acc_k<<<(BATCH * EMB + 255) / 256, 256, 0, stream>>>(
        emb1, user_ids, item_ids, w4, 2, fu, fi);

    prop_k<<<prop_blocks, 256, 0, stream>>>(row_start, csr_nbr, dinv, emb1, emb0);
    gather_acc_k<<<(BATCH * EMB + 255) / 256, 256, 0, stream>>>(
        emb0, user_ids, item_ids, w4, 3, fu, fi);

    // 7. scores
    score_k<<<(BATCH * EMB + 255) / 256, 256, 0, stream>>>(fu, fi, out);
}

// Round 3
// 582.216 us; speedup vs baseline: 2.5798x; 1.2950x over previous
//
#include <hip/hip_runtime.h>
#include <math.h>

#define NUM_USERS 100000
#define NUM_ITEMS 200000
#define N_NODES   300000   // NUM_USERS + NUM_ITEMS
#define EMB       64
#define NUM_INTER 1000000
#define N_EDGES   (2 * NUM_INTER)
#define MAX_SLOTS (N_EDGES + 7 * N_NODES + 16)   // rows padded to multiple of 8
#define BATCH     16384
#define SCAN_BLOCK 1024

// ---------- small kernels ----------

__global__ void softmax4_k(const float* __restrict__ lw, float* __restrict__ w) {
    if (threadIdx.x == 0 && blockIdx.x == 0) {
        float a = lw[0], b = lw[1], c = lw[2], d = lw[3];
        float m = fmaxf(fmaxf(a, b), fmaxf(c, d));
        float e0 = expf(a - m), e1 = expf(b - m), e2 = expf(c - m), e3 = expf(d - m);
        float s = e0 + e1 + e2 + e3;
        w[0] = e0 / s; w[1] = e1 / s; w[2] = e2 / s; w[3] = e3 / s;
    }
}

__global__ void degree_k(const int* __restrict__ iu, const int* __restrict__ ii,
                         int* __restrict__ deg) {
    int e = blockIdx.x * blockDim.x + threadIdx.x;
    if (e < NUM_INTER) {
        atomicAdd(&deg[iu[e]], 1);
        atomicAdd(&deg[NUM_USERS + ii[e]], 1);
    }
}

// dinv + padded degree (multiple of 8)
__global__ void dinv_k(const int* __restrict__ deg, float* __restrict__ dinv,
                       int* __restrict__ pdeg) {
    int n = blockIdx.x * blockDim.x + threadIdx.x;
    if (n < N_NODES) {
        int d = deg[n];
        dinv[n] = (d > 0) ? (1.0f / sqrtf((float)d)) : 0.0f;
        pdeg[n] = (d + 7) & ~7;
    }
}

// ---------- exclusive scan of pdeg -> row_start ----------

__global__ void block_sum_k(const int* __restrict__ v, int* __restrict__ bsum, int n) {
    __shared__ int lds[SCAN_BLOCK];
    int g = blockIdx.x * SCAN_BLOCK + threadIdx.x;
    lds[threadIdx.x] = (g < n) ? v[g] : 0;
    __syncthreads();
    for (int s = SCAN_BLOCK / 2; s > 0; s >>= 1) {
        if (threadIdx.x < s) lds[threadIdx.x] += lds[threadIdx.x + s];
        __syncthreads();
    }
    if (threadIdx.x == 0) bsum[blockIdx.x] = lds[0];
}

// single block; nb <= 512, exclusive scan in-place
__global__ void scan_bsum_k(int* __restrict__ bsum, int nb) {
    __shared__ int lds[512];
    int t = threadIdx.x;
    int v = (t < nb) ? bsum[t] : 0;
    lds[t] = v;
    __syncthreads();
    for (int ofs = 1; ofs < 512; ofs <<= 1) {
        int x = (t >= ofs) ? lds[t - ofs] : 0;
        __syncthreads();
        lds[t] += x;
        __syncthreads();
    }
    if (t < nb) bsum[t] = lds[t] - v;   // exclusive
}

__global__ void scan_block_k(const int* __restrict__ v, const int* __restrict__ bsum,
                             int* __restrict__ row_start, int n) {
    __shared__ int lds[SCAN_BLOCK];
    int g = blockIdx.x * SCAN_BLOCK + threadIdx.x;
    int x = (g < n) ? v[g] : 0;
    lds[threadIdx.x] = x;
    __syncthreads();
    for (int ofs = 1; ofs < SCAN_BLOCK; ofs <<= 1) {
        int y = (threadIdx.x >= ofs) ? lds[threadIdx.x - ofs] : 0;
        __syncthreads();
        lds[threadIdx.x] += y;
        __syncthreads();
    }
    if (g < n) row_start[g] = bsum[blockIdx.x] + lds[threadIdx.x] - x;  // exclusive
    if (g == n - 1) row_start[n] = bsum[blockIdx.x] + lds[threadIdx.x]; // inclusive total
}

// ---------- CSR fill (neighbor + fused edge weight) ----------

__global__ void fill_csr_k(const int* __restrict__ iu, const int* __restrict__ ii,
                           const int* __restrict__ row_start,
                           const float* __restrict__ dinv,
                           int* __restrict__ fill,
                           int* __restrict__ nbr, float* __restrict__ ew) {
    int e = blockIdx.x * blockDim.x + threadIdx.x;
    if (e < NUM_INTER) {
        int u  = iu[e];
        int it = NUM_USERS + ii[e];
        float w = dinv[u] * dinv[it];
        int p0 = row_start[u]  + atomicAdd(&fill[u],  1);
        nbr[p0] = it; ew[p0] = w;
        int p1 = row_start[it] + atomicAdd(&fill[it], 1);
        nbr[p1] = u;  ew[p1] = w;
    }
}

// ---------- propagation: 16 threads per node (float4 per lane), unroll-8 ----------

__global__ void prop_k(const int* __restrict__ row_start, const int* __restrict__ nbr,
                       const float* __restrict__ ew,
                       const float* __restrict__ in, float* __restrict__ out) {
    int t = blockIdx.x * blockDim.x + threadIdx.x;
    int node = t >> 4;
    int q = t & 15;
    if (node >= N_NODES) return;
    int beg = row_start[node], end = row_start[node + 1];
    const float4* in4 = (const float4*)in;
    float4 acc = make_float4(0.f, 0.f, 0.f, 0.f);
    for (int j = beg; j < end; j += 8) {
        int4   na = *(const int4*)(nbr + j);
        int4   nb = *(const int4*)(nbr + j + 4);
        float4 wa = *(const float4*)(ew + j);
        float4 wb = *(const float4*)(ew + j + 4);
        float4 g0 = in4[(size_t)na.x * 16 + q];
        float4 g1 = in4[(size_t)na.y * 16 + q];
        float4 g2 = in4[(size_t)na.z * 16 + q];
        float4 g3 = in4[(size_t)na.w * 16 + q];
        float4 g4 = in4[(size_t)nb.x * 16 + q];
        float4 g5 = in4[(size_t)nb.y * 16 + q];
        float4 g6 = in4[(size_t)nb.z * 16 + q];
        float4 g7 = in4[(size_t)nb.w * 16 + q];
        acc.x += wa.x * g0.x + wa.y * g1.x + wa.z * g2.x + wa.w * g3.x
               + wb.x * g4.x + wb.y * g5.x + wb.z * g6.x + wb.w * g7.x;
        acc.y += wa.x * g0.y + wa.y * g1.y + wa.z * g2.y + wa.w * g3.y
               + wb.x * g4.y + wb.y * g5.y + wb.z * g6.y + wb.w * g7.y;
        acc.z += wa.x * g0.z + wa.y * g1.z + wa.z * g2.z + wa.w * g3.z
               + wb.x * g4.z + wb.y * g5.z + wb.z * g6.z + wb.w * g7.z;
        acc.w += wa.x * g0.w + wa.y * g1.w + wa.z * g2.w + wa.w * g3.w
               + wb.x * g4.w + wb.y * g5.w + wb.z * g6.w + wb.w * g7.w;
    }
    ((float4*)out)[(size_t)node * 16 + q] = acc;
}

// ---------- epilogue ----------

__global__ void gather0_k(const float* __restrict__ ue, const float* __restrict__ ie,
                          const int* __restrict__ uid, const int* __restrict__ iid,
                          const float* __restrict__ w,
                          float* __restrict__ fu, float* __restrict__ fi) {
    int idx = blockIdx.x * blockDim.x + threadIdx.x;
    if (idx < BATCH * EMB) {
        int b = idx >> 6, d = idx & 63;
        float w0 = w[0];
        fu[idx] = w0 * ue[(size_t)uid[b] * EMB + d];
        fi[idx] = w0 * ie[(size_t)iid[b] * EMB + d];
    }
}

__global__ void gather_acc_k(const float* __restrict__ emb,
                             const int* __restrict__ uid, const int* __restrict__ iid,
                             const float* __restrict__ w, int wi,
                             float* __restrict__ fu, float* __restrict__ fi) {
    int idx = blockIdx.x * blockDim.x + threadIdx.x;
    if (idx < BATCH * EMB) {
        int b = idx >> 6, d = idx & 63;
        float wl = w[wi];
        fu[idx] += wl * emb[(size_t)uid[b] * EMB + d];
        fi[idx] += wl * emb[((size_t)NUM_USERS + iid[b]) * EMB + d];
    }
}

__global__ void score_k(const float* __restrict__ fu, const float* __restrict__ fi,
                        float* __restrict__ out) {
    int idx = blockIdx.x * blockDim.x + threadIdx.x;
    int b = idx >> 6, d = idx & 63;
    float v = fu[idx] * fi[idx];
    #pragma unroll
    for (int off = 32; off > 0; off >>= 1)
        v += __shfl_down(v, off, 64);
    if (d == 0) out[b] = v;
}

// ---------- launch ----------

extern "C" void kernel_launch(void* const* d_in, const int* in_sizes, int n_in,
                              void* d_out, int out_size, void* d_ws, size_t ws_size,
                              hipStream_t stream) {
    const float* user_emb = (const float*)d_in[0];
    const float* item_emb = (const float*)d_in[1];
    const float* layer_w  = (const float*)d_in[2];
    const int*   inter_u  = (const int*)d_in[3];
    const int*   inter_i  = (const int*)d_in[4];
    const int*   user_ids = (const int*)d_in[5];
    const int*   item_ids = (const int*)d_in[6];
    float* out = (float*)d_out;

    char* base = (char*)d_ws;
    size_t off = 0;
    auto alloc = [&](size_t bytes) -> char* {
        char* p = base + off;
        off = (off + bytes + 255) & ~(size_t)255;
        return p;
    };
    float* w4        = (float*)alloc(4 * sizeof(float));
    int*   deg       = (int*)  alloc((size_t)N_NODES * sizeof(int));
    int*   pdeg      = (int*)  alloc((size_t)N_NODES * sizeof(int));
    float* dinv      = (float*)alloc((size_t)N_NODES * sizeof(float));
    int*   row_start = (int*)  alloc(((size_t)N_NODES + 1) * sizeof(int));
    int*   bsum      = (int*)  alloc(512 * sizeof(int));
    int*   fill      = (int*)  alloc((size_t)N_NODES * sizeof(int));
    int*   csr_nbr   = (int*)  alloc((size_t)MAX_SLOTS * sizeof(int));
    float* csr_ew    = (float*)alloc((size_t)MAX_SLOTS * sizeof(float));
    float* emb0      = (float*)alloc((size_t)N_NODES * EMB * sizeof(float));
    float* emb1      = (float*)alloc((size_t)N_NODES * EMB * sizeof(float));
    float* fu        = (float*)alloc((size_t)BATCH * EMB * sizeof(float));
    float* fi        = (float*)alloc((size_t)BATCH * EMB * sizeof(float));

    const int nscan_blocks = (N_NODES + SCAN_BLOCK - 1) / SCAN_BLOCK;   // 293

    // 1. softmax weights
    softmax4_k<<<1, 64, 0, stream>>>(layer_w, w4);

    // 2. degrees + dinv + padded degree
    hipMemsetAsync(deg, 0, (size_t)N_NODES * sizeof(int), stream);
    degree_k<<<(NUM_INTER + 255) / 256, 256, 0, stream>>>(inter_u, inter_i, deg);
    dinv_k<<<(N_NODES + 255) / 256, 256, 0, stream>>>(deg, dinv, pdeg);

    // 3. exclusive scan pdeg -> row_start (padded CSR)
    block_sum_k<<<nscan_blocks, SCAN_BLOCK, 0, stream>>>(pdeg, bsum, N_NODES);
    scan_bsum_k<<<1, 512, 0, stream>>>(bsum, nscan_blocks);
    scan_block_k<<<nscan_blocks, SCAN_BLOCK, 0, stream>>>(pdeg, bsum, row_start, N_NODES);

    // 4. CSR fill: pad slots -> nbr=0, ew=0 (contribute nothing, hot line)
    hipMemsetAsync(csr_nbr, 0, (size_t)MAX_SLOTS * sizeof(int), stream);
    hipMemsetAsync(csr_ew,  0, (size_t)MAX_SLOTS * sizeof(float), stream);
    hipMemsetAsync(fill, 0, (size_t)N_NODES * sizeof(int), stream);
    fill_csr_k<<<(NUM_INTER + 255) / 256, 256, 0, stream>>>(
        inter_u, inter_i, row_start, dinv, fill, csr_nbr, csr_ew);

    // 5. emb0 = concat(user_emb, item_emb)
    hipMemcpyAsync(emb0, user_emb, (size_t)NUM_USERS * EMB * sizeof(float),
                   hipMemcpyDeviceToDevice, stream);
    hipMemcpyAsync(emb0 + (size_t)NUM_USERS * EMB, item_emb,
                   (size_t)NUM_ITEMS * EMB * sizeof(float),
                   hipMemcpyDeviceToDevice, stream);

    // 6. layer-0 contribution at queried nodes
    gather0_k<<<(BATCH * EMB + 255) / 256, 256, 0, stream>>>(
        user_emb, item_emb, user_ids, item_ids, w4, fu, fi);

    // 7. 3 propagation layers (uniform unroll-8, fused weights)
    const int prop_threads = N_NODES * 16;
    const int prop_blocks = (prop_threads + 255) / 256;
    prop_k<<<prop_blocks, 256, 0, stream>>>(row_start, csr_nbr, csr_ew, emb0, emb1);
    gather_acc_k<<<(BATCH * EMB + 255) / 256, 256, 0, stream>>>(
        emb1, user_ids, item_ids, w4, 1, fu, fi);

    prop_k<<<prop_blocks, 256, 0, stream>>>(row_start, csr_nbr, csr_ew, emb1, emb0);
    gather_acc_k<<<(BATCH * EMB + 255) / 256, 256, 0, stream>>>(
        emb0, user_ids, item_ids, w4, 2, fu, fi);

    prop_k<<<prop_blocks, 256, 0, stream>>>(row_start, csr_nbr, csr_ew, emb0, emb1);
    gather_acc_k<<<(BATCH * EMB + 255) / 256, 256, 0, stream>>>(
        emb1, user_ids, item_ids, w4, 3, fu, fi);

    // 8. scores
    score_k<<<(BATCH * EMB + 255) / 256, 256, 0, stream>>>(fu, fi, out);
}